// Round 1
// baseline (217.621 us; speedup 1.0000x reference)
//
#include <hip/hip_runtime.h>
#include <math.h>

// AFM forward. B=8192 samples, F=39 fields, E=A=16, P=741 pairs.
// One block of 256 threads per sample. Single fused pass over pairs
// (softmax without max-subtraction: scores are O(0.3), exp is safe in fp32).

#define BB 8192
#define FF 39
#define EE 16
#define AA 16
#define PP 741          // F*(F-1)/2
#define EMB_STRIDE 20   // 16 + 4 pad: keeps 16B alignment, spreads LDS banks

__global__ __launch_bounds__(256, 4)
void afm_kernel(const int*   __restrict__ fidx,
                const float* __restrict__ fval,
                const float* __restrict__ fow,
                const float* __restrict__ emb_table,
                const float* __restrict__ bias,
                const float* __restrict__ attn_w,   // [E][A] row-major
                const float* __restrict__ attn_b,   // [A]
                const float* __restrict__ proj_h,   // [A]
                const float* __restrict__ proj_p,   // [E]
                float*       __restrict__ out)
{
    __shared__ float s_emb[FF * EMB_STRIDE];   // scaled embeddings
    __shared__ float s_fo[FF];                 // first-order terms
    __shared__ int   s_idx[FF];
    __shared__ float s_val[FF];
    __shared__ unsigned char s_pi[768];
    __shared__ unsigned char s_pj[768];
    __shared__ float s_red[4 * 17];            // 4 waves x (16 pooled + Z)

    const int b    = blockIdx.x;
    const int tid  = threadIdx.x;
    const int lane = tid & 63;
    const int wid  = tid >> 6;

    // ---- Step A: indices, values, first-order gather (threads 0..38) ----
    if (tid < FF) {
        int   ix = fidx[b * FF + tid];
        float v  = fval[b * FF + tid];
        s_idx[tid] = ix;
        s_val[tid] = v;
        s_fo[tid]  = fow[ix] * v;
    }
    // ---- pair tables: threads 64..101 each fill one row i ----
    if (tid >= 64 && tid - 64 < FF - 1) {
        int i = tid - 64;
        int base = (i * (2 * FF - i - 1)) >> 1;   // #pairs before row i
        for (int j = i + 1; j < FF; ++j) {
            s_pi[base] = (unsigned char)i;
            s_pj[base] = (unsigned char)j;
            ++base;
        }
    }
    __syncthreads();

    // ---- Step B: gather embedding rows (float4), scale by value ----
    if (tid < FF * 4) {
        int row = tid >> 2, q = tid & 3;
        const float4* src = (const float4*)emb_table;
        float4 v = src[(size_t)s_idx[row] * 4 + q];
        float sv = s_val[row];
        float* dst = &s_emb[row * EMB_STRIDE + q * 4];
        dst[0] = v.x * sv; dst[1] = v.y * sv; dst[2] = v.z * sv; dst[3] = v.w * sv;
    }
    __syncthreads();

    // ---- Fused pass over pairs: bi -> att -> score -> exp-weighted pool ----
    float pooled[EE];
    #pragma unroll
    for (int e = 0; e < EE; ++e) pooled[e] = 0.f;
    float zloc = 0.f;

    for (int p = tid; p < PP; p += 256) {
        int i = s_pi[p], j = s_pj[p];
        const float4* ei = (const float4*)&s_emb[i * EMB_STRIDE];
        const float4* ej = (const float4*)&s_emb[j * EMB_STRIDE];
        float bi[EE];
        #pragma unroll
        for (int q = 0; q < 4; ++q) {
            float4 a4 = ei[q], b4 = ej[q];
            bi[q * 4 + 0] = a4.x * b4.x;
            bi[q * 4 + 1] = a4.y * b4.y;
            bi[q * 4 + 2] = a4.z * b4.z;
            bi[q * 4 + 3] = a4.w * b4.w;
        }
        // attention MLP: attn_* accessed with uniform indices -> s_load (SGPR)
        float s = 0.f;
        #pragma unroll
        for (int a = 0; a < AA; ++a) {
            float acc = attn_b[a];
            #pragma unroll
            for (int e = 0; e < EE; ++e)
                acc = fmaf(bi[e], attn_w[e * AA + a], acc);
            s = fmaf(fmaxf(acc, 0.f), proj_h[a], s);
        }
        float w = __expf(s);          // no max-subtraction needed: |s| small
        zloc += w;
        #pragma unroll
        for (int e = 0; e < EE; ++e)
            pooled[e] = fmaf(w, bi[e], pooled[e]);
    }

    // ---- wave-level reduction of pooled[16] and Z ----
    #pragma unroll
    for (int e = 0; e < EE; ++e) {
        float v = pooled[e];
        for (int off = 32; off > 0; off >>= 1) v += __shfl_down(v, off);
        pooled[e] = v;
    }
    for (int off = 32; off > 0; off >>= 1) zloc += __shfl_down(zloc, off);

    if (lane == 0) {
        #pragma unroll
        for (int e = 0; e < EE; ++e) s_red[wid * 17 + e] = pooled[e];
        s_red[wid * 17 + 16] = zloc;
    }
    __syncthreads();

    // ---- final combine (thread 0) ----
    if (tid == 0) {
        float aw = 0.f;
        #pragma unroll
        for (int e = 0; e < EE; ++e) {
            float pe = s_red[e] + s_red[17 + e] + s_red[34 + e] + s_red[51 + e];
            aw = fmaf(pe, proj_p[e], aw);
        }
        float Z = s_red[16] + s_red[33] + s_red[50] + s_red[67];
        float yf = 0.f;
        for (int f = 0; f < FF; ++f) yf += s_fo[f];
        float y = bias[0] + yf + aw / Z;
        out[b] = 1.f / (1.f + __expf(-y));
    }
}

extern "C" void kernel_launch(void* const* d_in, const int* in_sizes, int n_in,
                              void* d_out, int out_size, void* d_ws, size_t ws_size,
                              hipStream_t stream) {
    const int*   fidx      = (const int*)  d_in[0];
    const float* fval      = (const float*)d_in[1];
    const float* fow       = (const float*)d_in[2];
    const float* emb_table = (const float*)d_in[3];
    const float* bias      = (const float*)d_in[4];
    const float* attn_w    = (const float*)d_in[5];
    const float* attn_b    = (const float*)d_in[6];
    const float* proj_h    = (const float*)d_in[7];
    const float* proj_p    = (const float*)d_in[8];
    float* out = (float*)d_out;

    afm_kernel<<<BB, 256, 0, stream>>>(fidx, fval, fow, emb_table, bias,
                                       attn_w, attn_b, proj_h, proj_p, out);
}

// Round 2
// 174.814 us; speedup vs baseline: 1.2449x; 1.2449x over previous
//
#include <hip/hip_runtime.h>
#include <math.h>

// AFM forward. B=8192, F=39, E=A=16, P=741 pairs. One block (256 thr) / sample.
// Round 2: fully scalarized registers (no indexed private arrays -> no
// rolled-loop/scratch bloat), 3 pairs per thread straight-line, LDS-transpose
// final reduction. Softmax without max-subtraction (scores are O(0.1), safe).

#define BB 8192
#define FF 39
#define EE 16
#define AA 16
#define PP 741          // F*(F-1)/2
#define ESTR 20         // emb row stride in floats (5 float4s)
#define PSTR 20         // pool row stride in floats

__global__ __launch_bounds__(256, 4)
void afm_kernel(const int*   __restrict__ fidx,
                const float* __restrict__ fval,
                const float* __restrict__ fow,
                const float* __restrict__ emb_table,
                const float* __restrict__ bias,
                const float* __restrict__ aw_,   // [E][A] row-major
                const float* __restrict__ ab_,   // [A]
                const float* __restrict__ ph_,   // [A]
                const float* __restrict__ pp_,   // [E]
                float*       __restrict__ out)
{
    __shared__ __align__(16) float s_emb[FF * ESTR];     // 3120 B
    __shared__ __align__(16) float s_pool[256 * PSTR];   // 20480 B
    __shared__ float s_red[16 * 16];
    __shared__ int   s_idx[FF];
    __shared__ float s_val[FF];
    __shared__ unsigned char s_pi[768];
    __shared__ unsigned char s_pj[768];
    __shared__ float s_zw[4];
    __shared__ float s_foS;

    const int b    = blockIdx.x;
    const int tid  = threadIdx.x;
    const int lane = tid & 63;
    const int wid  = tid >> 6;

    // ---- Step A: indices/values/first-order (wave 0), pair tables (wave 1) --
    float fo = 0.f;
    if (tid < 64) {
        if (tid < FF) {
            int   ix = fidx[b * FF + tid];
            float v  = fval[b * FF + tid];
            s_idx[tid] = ix;
            s_val[tid] = v;
            fo = fow[ix] * v;
        }
        // wave-0 butterfly reduce of first-order term
        #pragma unroll
        for (int m = 32; m >= 1; m >>= 1) fo += __shfl_xor(fo, m);
        if (tid == 0) s_foS = fo;
    }
    if (tid >= 64 && tid - 64 < FF - 1) {
        int i = tid - 64;
        int base = (i * (2 * FF - i - 1)) >> 1;
        for (int j = i + 1; j < FF; ++j) {
            s_pi[base] = (unsigned char)i;
            s_pj[base] = (unsigned char)j;
            ++base;
        }
    }
    __syncthreads();

    // ---- Step B: gather + scale embedding rows (float4) ----
    if (tid < FF * 4) {
        int row = tid >> 2, q = tid & 3;
        const float4* src = (const float4*)emb_table;
        float4 v = src[(size_t)s_idx[row] * 4 + q];
        float sv = s_val[row];
        float4* dst = (float4*)&s_emb[row * ESTR];
        dst[q] = make_float4(v.x * sv, v.y * sv, v.z * sv, v.w * sv);
    }
    __syncthreads();

    // ---- Main: 3 pairs per thread, straight-line, all in named registers ----
    const float4* base4 = (const float4*)s_emb;
    const int pA = tid, pB = tid + 256, pC = tid + 512;
    const bool vC = (pC < PP);
    const int pCc = vC ? pC : 0;

    int iA = s_pi[pA], jA = s_pj[pA];
    int iB = s_pi[pB], jB = s_pj[pB];
    int iC = s_pi[pCc], jC = s_pj[pCc];

    float4 bA0, bA1, bA2, bA3, bB0, bB1, bB2, bB3, bC0, bC1, bC2, bC3;
#define LOADBI(D0,D1,D2,D3, ii, jj)                                   \
    {                                                                 \
        float4 x0 = base4[(ii)*5+0], x1 = base4[(ii)*5+1];            \
        float4 x2 = base4[(ii)*5+2], x3 = base4[(ii)*5+3];            \
        float4 y0 = base4[(jj)*5+0], y1 = base4[(jj)*5+1];            \
        float4 y2 = base4[(jj)*5+2], y3 = base4[(jj)*5+3];            \
        D0 = make_float4(x0.x*y0.x, x0.y*y0.y, x0.z*y0.z, x0.w*y0.w); \
        D1 = make_float4(x1.x*y1.x, x1.y*y1.y, x1.z*y1.z, x1.w*y1.w); \
        D2 = make_float4(x2.x*y2.x, x2.y*y2.y, x2.z*y2.z, x2.w*y2.w); \
        D3 = make_float4(x3.x*y3.x, x3.y*y3.y, x3.z*y3.z, x3.w*y3.w); \
    }
    LOADBI(bA0,bA1,bA2,bA3, iA, jA);
    LOADBI(bB0,bB1,bB2,bB3, iB, jB);
    LOADBI(bC0,bC1,bC2,bC3, iC, jC);

#define DOT16(acc, B0,B1,B2,B3)                                       \
    acc = fmaf((B0).x, w0,  acc); acc = fmaf((B0).y, w1,  acc);       \
    acc = fmaf((B0).z, w2,  acc); acc = fmaf((B0).w, w3,  acc);       \
    acc = fmaf((B1).x, w4,  acc); acc = fmaf((B1).y, w5,  acc);       \
    acc = fmaf((B1).z, w6,  acc); acc = fmaf((B1).w, w7,  acc);       \
    acc = fmaf((B2).x, w8,  acc); acc = fmaf((B2).y, w9,  acc);       \
    acc = fmaf((B2).z, w10, acc); acc = fmaf((B2).w, w11, acc);       \
    acc = fmaf((B3).x, w12, acc); acc = fmaf((B3).y, w13, acc);       \
    acc = fmaf((B3).z, w14, acc); acc = fmaf((B3).w, w15, acc);

    float sA = 0.f, sB = 0.f, sC = 0.f;
    #pragma unroll
    for (int a = 0; a < AA; ++a) {
        const float w0  = aw_[  0 + a], w1  = aw_[ 16 + a];
        const float w2  = aw_[ 32 + a], w3  = aw_[ 48 + a];
        const float w4  = aw_[ 64 + a], w5  = aw_[ 80 + a];
        const float w6  = aw_[ 96 + a], w7  = aw_[112 + a];
        const float w8  = aw_[128 + a], w9  = aw_[144 + a];
        const float w10 = aw_[160 + a], w11 = aw_[176 + a];
        const float w12 = aw_[192 + a], w13 = aw_[208 + a];
        const float w14 = aw_[224 + a], w15 = aw_[240 + a];
        const float bb  = ab_[a];
        const float hh  = ph_[a];
        float accA = bb, accB = bb, accC = bb;
        DOT16(accA, bA0, bA1, bA2, bA3);
        DOT16(accB, bB0, bB1, bB2, bB3);
        DOT16(accC, bC0, bC1, bC2, bC3);
        sA = fmaf(fmaxf(accA, 0.f), hh, sA);
        sB = fmaf(fmaxf(accB, 0.f), hh, sB);
        sC = fmaf(fmaxf(accC, 0.f), hh, sC);
    }

    const float wA = __expf(sA);
    const float wB = __expf(sB);
    const float wC = vC ? __expf(sC) : 0.f;
    float z = wA + wB + wC;

    // wave-level z reduction (registers only)
    float zw = z;
    #pragma unroll
    for (int m = 32; m >= 1; m >>= 1) zw += __shfl_xor(zw, m);
    if (lane == 0) s_zw[wid] = zw;

#define POOL(P, A4,B4,C4)                                   \
    P = make_float4(                                        \
        fmaf(wC,(C4).x, fmaf(wB,(B4).x, wA*(A4).x)),        \
        fmaf(wC,(C4).y, fmaf(wB,(B4).y, wA*(A4).y)),        \
        fmaf(wC,(C4).z, fmaf(wB,(B4).z, wA*(A4).z)),        \
        fmaf(wC,(C4).w, fmaf(wB,(B4).w, wA*(A4).w)));
    float4 p0, p1, p2, p3;
    POOL(p0, bA0, bB0, bC0);
    POOL(p1, bA1, bB1, bC1);
    POOL(p2, bA2, bB2, bC2);
    POOL(p3, bA3, bB3, bC3);

    float4* pr = (float4*)&s_pool[tid * PSTR];
    pr[0] = p0; pr[1] = p1; pr[2] = p2; pr[3] = p3;
    __syncthreads();

    // ---- Phase 1: transpose-reduce 256 rows -> 16 partials per element ----
    {
        const int g = tid >> 4, e = tid & 15;
        float t = 0.f;
        #pragma unroll
        for (int s = 0; s < 16; ++s)
            t += s_pool[(g * 16 + s) * PSTR + e];
        s_red[e * 16 + g] = t;
    }
    __syncthreads();

    // ---- Phase 2: threads 0..15 finish; lane 0 writes output ----
    if (tid < 16) {
        float tot = 0.f;
        #pragma unroll
        for (int g = 0; g < 16; ++g) tot += s_red[tid * 16 + g];
        float val = tot * pp_[tid];
        #pragma unroll
        for (int m = 8; m >= 1; m >>= 1) val += __shfl_xor(val, m);
        if (tid == 0) {
            float Z = s_zw[0] + s_zw[1] + s_zw[2] + s_zw[3];
            float y = bias[0] + s_foS + val / Z;
            out[b] = 1.f / (1.f + __expf(-y));
        }
    }
}

extern "C" void kernel_launch(void* const* d_in, const int* in_sizes, int n_in,
                              void* d_out, int out_size, void* d_ws, size_t ws_size,
                              hipStream_t stream) {
    const int*   fidx      = (const int*)  d_in[0];
    const float* fval      = (const float*)d_in[1];
    const float* fow       = (const float*)d_in[2];
    const float* emb_table = (const float*)d_in[3];
    const float* bias      = (const float*)d_in[4];
    const float* attn_w    = (const float*)d_in[5];
    const float* attn_b    = (const float*)d_in[6];
    const float* proj_h    = (const float*)d_in[7];
    const float* proj_p    = (const float*)d_in[8];
    float* out = (float*)d_out;

    afm_kernel<<<BB, 256, 0, stream>>>(fidx, fval, fow, emb_table, bias,
                                       attn_w, attn_b, proj_h, proj_p, out);
}

// Round 3
// 143.348 us; speedup vs baseline: 1.5181x; 1.2195x over previous
//
#include <hip/hip_runtime.h>
#include <math.h>

// AFM forward, round 3: MFMA for the attention MLP.
// One wave = one sample (4 samples / 256-thr block). Per 16-pair tile:
//   B-frag = bi^T (fp32 products -> bf16 truncate), A-frag = attn_W^T (K 16->32
//   zero-padded; quads 2/3 of B are don't-care and mirror quads 0/1),
//   D[a][m] = att scores (+bias via acc init). relu*h dot in-lane, quad
//   allreduce via shfl_xor(16/32), exp, fused fp32 pooling FMA.
// Layouts per guide §3 (m89/m91 verified): A[m=lane&15][k=quad*8+j],
// B[k=quad*8+j][n=lane&15], C/D col=lane&15 row=quad*4+reg.

#define BB 8192
#define FF 39
#define PP 741
#define NT 47            // ceil(741/16) tiles per sample
#define RSTR 20          // emb row stride in floats (80 B: 16B-aligned, bank-spread)
#define SSTR (FF * RSTR) // per-sample floats (780)

typedef short bf16x8 __attribute__((ext_vector_type(8)));
typedef float f32x4  __attribute__((ext_vector_type(4)));

static __device__ __forceinline__ int pack2(float a, float b) {
    // two fp32 -> packed bf16 pair (truncation; inputs ~1e-4, error negligible)
    unsigned ua = __builtin_bit_cast(unsigned, a);
    unsigned ub = __builtin_bit_cast(unsigned, b);
    return (int)((ua >> 16) | (ub & 0xFFFF0000u));
}

__global__ __launch_bounds__(256)
void afm_kernel(const int*   __restrict__ fidx,
                const float* __restrict__ fval,
                const float* __restrict__ fow,
                const float* __restrict__ emb,
                const float* __restrict__ bias,
                const float* __restrict__ aw_,   // [E=16][A=16] row-major
                const float* __restrict__ ab_,   // [16]
                const float* __restrict__ ph_,   // [16]
                const float* __restrict__ pp_,   // [16]
                float*       __restrict__ out)
{
    __shared__ __align__(16) float s_emb[4 * SSTR];   // 12480 B
    __shared__ unsigned s_pij[NT * 16];               // 3008 B

    const int tid  = threadIdx.x;
    const int wid  = tid >> 6;
    const int lane = tid & 63;
    const int c    = lane & 15;      // pair slot within tile / A-col
    const int quad = lane >> 4;
    const int smp  = blockIdx.x * 4 + wid;

    // ---- pair table (block-shared): packed byte offsets (i*80)<<16 | (j*80) --
    if (tid < FF - 1) {
        int i = tid;
        int base = (i * (2 * FF - i - 1)) >> 1;
        for (int j = i + 1; j < FF; ++j)
            s_pij[base++] = ((unsigned)(i * 80) << 16) | (unsigned)(j * 80);
    } else if (tid == FF - 1) {
        for (int e = PP; e < NT * 16; ++e) s_pij[e] = 0u;   // dead slots -> (0,0)
    }

    // ---- per-wave: indices, values, first-order term ----
    int ixr = 0; float vr = 0.f, fo = 0.f;
    if (lane < FF) {
        ixr = fidx[smp * FF + lane];
        vr  = fval[smp * FF + lane];
        fo  = fow[ixr] * vr;
    }
    #pragma unroll
    for (int m = 1; m < 64; m <<= 1) fo += __shfl_xor(fo, m);

    // ---- stage scaled embedding rows (this wave's sample only; no barrier
    //      needed for this data — same-wave LDS ordering) ----
    float* my = &s_emb[wid * SSTR];
    for (int u = lane; u < FF * 4; u += 64) {
        int row = u >> 2, q4 = u & 3;
        int   ix = __shfl(ixr, row);
        float v  = __shfl(vr,  row);
        const float4 ev = ((const float4*)emb)[(size_t)ix * 4 + q4];
        *(float4*)&my[row * RSTR + q4 * 4] =
            make_float4(ev.x * v, ev.y * v, ev.z * v, ev.w * v);
    }

    // ---- constant fragments ----
    const f32x4 abf = ((const f32x4*)ab_)[quad];   // acc init: ab[a=quad*4+reg]
    const f32x4 hf  = ((const f32x4*)ph_)[quad];   // h[a=quad*4+reg]
    bf16x8 wfrag;                                  // A = W^T, zeros for k>=16
    {
        float t0 = 0.f, t1 = 0.f, t2 = 0.f, t3 = 0.f,
              t4 = 0.f, t5 = 0.f, t6 = 0.f, t7 = 0.f;
        if (quad < 2) {
            const float* base = aw_ + (quad * 8) * 16 + c;   // attn_w[e][a=c]
            t0 = base[0];   t1 = base[16];  t2 = base[32];  t3 = base[48];
            t4 = base[64];  t5 = base[80];  t6 = base[96];  t7 = base[112];
        }
        union { int i[4]; bf16x8 v; } u;
        u.i[0] = pack2(t0, t1); u.i[1] = pack2(t2, t3);
        u.i[2] = pack2(t4, t5); u.i[3] = pack2(t6, t7);
        wfrag = u.v;
    }

    __syncthreads();   // covers s_pij (and staging, harmlessly)

    // ---- main loop: 47 MFMA tiles of 16 pairs ----
    const char* bpre = (const char*)my + (quad & 1) * 32;  // e-half by quad&1
    float p0=0.f,p1=0.f,p2=0.f,p3=0.f,p4=0.f,p5=0.f,p6=0.f,p7=0.f;
    float z = 0.f;
    int pidx = c;
    for (int t = 0; t < NT; ++t, pidx += 16) {
        unsigned pk = s_pij[t * 16 + c];
        const float4* ei = (const float4*)(bpre + (pk >> 16));
        const float4* ej = (const float4*)(bpre + (pk & 0xFFFFu));
        float4 a0 = ei[0], a1 = ei[1];
        float4 b0 = ej[0], b1 = ej[1];
        float m0 = a0.x*b0.x, m1 = a0.y*b0.y, m2 = a0.z*b0.z, m3 = a0.w*b0.w;
        float m4 = a1.x*b1.x, m5 = a1.y*b1.y, m6 = a1.z*b1.z, m7 = a1.w*b1.w;
        union { int i[4]; bf16x8 v; } u;
        u.i[0] = pack2(m0, m1); u.i[1] = pack2(m2, m3);
        u.i[2] = pack2(m4, m5); u.i[3] = pack2(m6, m7);
        f32x4 acc = abf;
        acc = __builtin_amdgcn_mfma_f32_16x16x32_bf16(wfrag, u.v, acc, 0, 0, 0);
        // relu * h, reduce over a: in-lane (4 rows) then across quads
        float s = fmaf(fmaxf(acc[0], 0.f), hf[0],
                  fmaf(fmaxf(acc[1], 0.f), hf[1],
                  fmaf(fmaxf(acc[2], 0.f), hf[2],
                       fmaxf(acc[3], 0.f) * hf[3])));
        s += __shfl_xor(s, 16);
        s += __shfl_xor(s, 32);
        float w = __expf(s);
        w = (pidx < PP) ? w : 0.f;   // mask dead slots of last tile
        z += w;
        p0 = fmaf(w, m0, p0); p1 = fmaf(w, m1, p1);
        p2 = fmaf(w, m2, p2); p3 = fmaf(w, m3, p3);
        p4 = fmaf(w, m4, p4); p5 = fmaf(w, m5, p5);
        p6 = fmaf(w, m6, p6); p7 = fmaf(w, m7, p7);
    }

    // ---- epilogue: aw = pooled . p  (lane partials then full-wave reduce) ----
    const float4 pf0 = ((const float4*)pp_)[(quad & 1) * 2];
    const float4 pf1 = ((const float4*)pp_)[(quad & 1) * 2 + 1];
    float awp = fmaf(p0, pf0.x, fmaf(p1, pf0.y, fmaf(p2, pf0.z,
                fmaf(p3, pf0.w, fmaf(p4, pf1.x, fmaf(p5, pf1.y,
                fmaf(p6, pf1.z, p7 * pf1.w)))))));
    #pragma unroll
    for (int m = 1; m < 64; m <<= 1) {
        awp += __shfl_xor(awp, m);
        z   += __shfl_xor(z, m);
    }
    if (lane == 0) {
        // awp summed over lanes = 2*aw (e-halves duplicated over quads);
        // z summed = 4*Z. (aw)/(Z) = (awp/2)/(z/4) = 2*awp/z.
        float y = bias[0] + fo + 2.f * awp / z;
        out[smp] = 1.f / (1.f + __expf(-y));
    }
}

extern "C" void kernel_launch(void* const* d_in, const int* in_sizes, int n_in,
                              void* d_out, int out_size, void* d_ws, size_t ws_size,
                              hipStream_t stream) {
    const int*   fidx      = (const int*)  d_in[0];
    const float* fval      = (const float*)d_in[1];
    const float* fow       = (const float*)d_in[2];
    const float* emb_table = (const float*)d_in[3];
    const float* bias      = (const float*)d_in[4];
    const float* attn_w    = (const float*)d_in[5];
    const float* attn_b    = (const float*)d_in[6];
    const float* proj_h    = (const float*)d_in[7];
    const float* proj_p    = (const float*)d_in[8];
    float* out = (float*)d_out;

    afm_kernel<<<BB / 4, 256, 0, stream>>>(fidx, fval, fow, emb_table, bias,
                                           attn_w, attn_b, proj_h, proj_p, out);
}

// Round 4
// 132.609 us; speedup vs baseline: 1.6411x; 1.0810x over previous
//
#include <hip/hip_runtime.h>
#include <math.h>

// AFM forward, round 4: 32x32x16 MFMA (K=16 exact, 32 pairs per MFMA).
// One wave = one sample. B-frag: lane (n, h=lane>>5) holds e-half h of pair n
// -> every LDS byte read feeds a live fragment slot (r3 wasted half on the
// zero-padded K). A = attn_W^T in rows m<16 (rows 16..31 zero). Bias via
// loop-invariant C-init. Score: in-lane 8-term relu dot + one shfl_xor(32).
// Pooling stays fp32 on the products already in registers.
// C/D layout (verified m74/m101): col=lane&31, row=(reg&3)+8*(reg>>2)+4*(lane>>5).
// A/B k-map mirrors 16x16x32 (k = (lane>>5)*8+j); any k-permutation cancels
// since A and B share the same map.

#define BB 8192
#define FF 39
#define PP 741
#define NT 24            // ceil(741/32) MFMA tiles per sample
#define RSTR 20          // emb row stride in floats (80 B, 16B-aligned)
#define SSTR (FF * RSTR) // 780 floats per sample

typedef short bf16x8 __attribute__((ext_vector_type(8)));
typedef float f32x4  __attribute__((ext_vector_type(4)));
typedef float f32x16 __attribute__((ext_vector_type(16)));

static __device__ __forceinline__ int pack2(float a, float b) {
    unsigned ua = __builtin_bit_cast(unsigned, a);
    unsigned ub = __builtin_bit_cast(unsigned, b);
    return (int)((ua >> 16) | (ub & 0xFFFF0000u));
}

__global__ __launch_bounds__(256)
void afm_kernel(const int*   __restrict__ fidx,
                const float* __restrict__ fval,
                const float* __restrict__ fow,
                const float* __restrict__ emb,
                const float* __restrict__ bias,
                const float* __restrict__ aw_,   // [E=16][A=16] row-major
                const float* __restrict__ ab_,   // [16]
                const float* __restrict__ ph_,   // [16]
                const float* __restrict__ pp_,   // [16]
                float*       __restrict__ out)
{
    __shared__ __align__(16) float s_emb[4 * SSTR];   // 12480 B
    __shared__ unsigned s_pij[NT * 32];               // 3072 B

    const int tid  = threadIdx.x;
    const int wid  = tid >> 6;
    const int lane = tid & 63;
    const int n    = lane & 31;      // pair slot within tile / A row m
    const int h    = lane >> 5;      // e-half / k-half
    const int smp  = blockIdx.x * 4 + wid;

    // ---- pair table (block-shared): (i*80)<<16 | (j*80) byte offsets ----
    if (tid < FF - 1) {
        int i = tid;
        int base = (i * (2 * FF - i - 1)) >> 1;
        for (int j = i + 1; j < FF; ++j)
            s_pij[base++] = ((unsigned)(i * 80) << 16) | (unsigned)(j * 80);
    } else if (tid == FF - 1) {
        for (int e = PP; e < NT * 32; ++e) s_pij[e] = 0u;  // dead slots
    }

    // ---- per-wave: indices, values, first-order term ----
    int ixr = 0; float vr = 0.f, fo = 0.f;
    if (lane < FF) {
        ixr = fidx[smp * FF + lane];
        vr  = fval[smp * FF + lane];
        fo  = fow[ixr] * vr;
    }
    #pragma unroll
    for (int m = 1; m < 64; m <<= 1) fo += __shfl_xor(fo, m);

    // ---- stage scaled embedding rows (same-wave LDS ordering) ----
    float* my = &s_emb[wid * SSTR];
    for (int u = lane; u < FF * 4; u += 64) {
        int row = u >> 2, q4 = u & 3;
        int   ix = __shfl(ixr, row);
        float v  = __shfl(vr,  row);
        const float4 ev = ((const float4*)emb)[(size_t)ix * 4 + q4];
        *(float4*)&my[row * RSTR + q4 * 4] =
            make_float4(ev.x * v, ev.y * v, ev.z * v, ev.w * v);
    }

    // ---- constant fragments ----
    // h-dot coefficients for this lane's 8 valid acc regs:
    //   reg 0..3 -> a = reg + 4h ; reg 4..7 -> a = 8 + (reg-4) + 4h
    const f32x4 h_lo = ((const f32x4*)ph_)[h];
    const f32x4 h_hi = ((const f32x4*)ph_)[h + 2];

    f32x16 cinit;                                 // bias in rows a<16, 0 else
    {
        const f32x4 ab_lo = ((const f32x4*)ab_)[h];
        const f32x4 ab_hi = ((const f32x4*)ab_)[h + 2];
        cinit[0] = ab_lo[0]; cinit[1] = ab_lo[1];
        cinit[2] = ab_lo[2]; cinit[3] = ab_lo[3];
        cinit[4] = ab_hi[0]; cinit[5] = ab_hi[1];
        cinit[6] = ab_hi[2]; cinit[7] = ab_hi[3];
        #pragma unroll
        for (int r = 8; r < 16; ++r) cinit[r] = 0.f;
    }

    bf16x8 wfrag;                                 // A = W^T, rows m>=16 zero
    {
        float t0 = 0.f, t1 = 0.f, t2 = 0.f, t3 = 0.f,
              t4 = 0.f, t5 = 0.f, t6 = 0.f, t7 = 0.f;
        if (n < 16) {
            const float* base = aw_ + (8 * h) * 16 + n;  // W[k=8h+j][m=n]
            t0 = base[0];   t1 = base[16];  t2 = base[32];  t3 = base[48];
            t4 = base[64];  t5 = base[80];  t6 = base[96];  t7 = base[112];
        }
        union { int i[4]; bf16x8 v; } u;
        u.i[0] = pack2(t0, t1); u.i[1] = pack2(t2, t3);
        u.i[2] = pack2(t4, t5); u.i[3] = pack2(t6, t7);
        wfrag = u.v;
    }

    __syncthreads();   // covers s_pij (+ staging, harmlessly)

    // ---- main loop: 24 MFMA tiles of 32 pairs ----
    const char* bpre = (const char*)my + h * 32;  // this lane's e-half
    float p0=0.f,p1=0.f,p2=0.f,p3=0.f,p4=0.f,p5=0.f,p6=0.f,p7=0.f;
    float z = 0.f;
    int pidx = n;
    #pragma unroll 4
    for (int t = 0; t < NT; ++t, pidx += 32) {
        unsigned pk = s_pij[t * 32 + n];
        const float4* ei = (const float4*)(bpre + (pk >> 16));
        const float4* ej = (const float4*)(bpre + (pk & 0xFFFFu));
        float4 a0 = ei[0], a1 = ei[1];
        float4 b0 = ej[0], b1 = ej[1];
        float m0 = a0.x*b0.x, m1 = a0.y*b0.y, m2 = a0.z*b0.z, m3 = a0.w*b0.w;
        float m4 = a1.x*b1.x, m5 = a1.y*b1.y, m6 = a1.z*b1.z, m7 = a1.w*b1.w;
        union { int i[4]; bf16x8 v; } u;
        u.i[0] = pack2(m0, m1); u.i[1] = pack2(m2, m3);
        u.i[2] = pack2(m4, m5); u.i[3] = pack2(m6, m7);
        f32x16 d = __builtin_amdgcn_mfma_f32_32x32x16_bf16(wfrag, u.v, cinit,
                                                           0, 0, 0);
        float s = fmaf(fmaxf(d[0], 0.f), h_lo[0],
                  fmaf(fmaxf(d[1], 0.f), h_lo[1],
                  fmaf(fmaxf(d[2], 0.f), h_lo[2],
                  fmaf(fmaxf(d[3], 0.f), h_lo[3],
                  fmaf(fmaxf(d[4], 0.f), h_hi[0],
                  fmaf(fmaxf(d[5], 0.f), h_hi[1],
                  fmaf(fmaxf(d[6], 0.f), h_hi[2],
                       fmaxf(d[7], 0.f) * h_hi[3])))))));
        s += __shfl_xor(s, 32);                  // sum the two k-halves
        float w = __expf(s);
        w = (pidx < PP) ? w : 0.f;               // mask dead slots
        z += w;
        p0 = fmaf(w, m0, p0); p1 = fmaf(w, m1, p1);
        p2 = fmaf(w, m2, p2); p3 = fmaf(w, m3, p3);
        p4 = fmaf(w, m4, p4); p5 = fmaf(w, m5, p5);
        p6 = fmaf(w, m6, p6); p7 = fmaf(w, m7, p7);
    }

    // ---- epilogue: aw = pooled . p ----
    const float4 pf0 = ((const float4*)pp_)[2 * h];
    const float4 pf1 = ((const float4*)pp_)[2 * h + 1];
    float awp = fmaf(p0, pf0.x, fmaf(p1, pf0.y, fmaf(p2, pf0.z,
                fmaf(p3, pf0.w, fmaf(p4, pf1.x, fmaf(p5, pf1.y,
                fmaf(p6, pf1.z, p7 * pf1.w)))))));
    #pragma unroll
    for (int m = 1; m < 64; m <<= 1) {
        awp += __shfl_xor(awp, m);
        z   += __shfl_xor(z, m);
    }
    if (lane == 0) {
        // lane-sum awp = aw (each pair-half once); lane-sum z = 2*Z.
        float y = bias[0] + fo + 2.f * awp / z;
        out[smp] = 1.f / (1.f + __expf(-y));
    }
}

extern "C" void kernel_launch(void* const* d_in, const int* in_sizes, int n_in,
                              void* d_out, int out_size, void* d_ws, size_t ws_size,
                              hipStream_t stream) {
    const int*   fidx      = (const int*)  d_in[0];
    const float* fval      = (const float*)d_in[1];
    const float* fow       = (const float*)d_in[2];
    const float* emb_table = (const float*)d_in[3];
    const float* bias      = (const float*)d_in[4];
    const float* attn_w    = (const float*)d_in[5];
    const float* attn_b    = (const float*)d_in[6];
    const float* proj_h    = (const float*)d_in[7];
    const float* proj_p    = (const float*)d_in[8];
    float* out = (float*)d_out;

    afm_kernel<<<BB / 4, 256, 0, stream>>>(fidx, fval, fow, emb_table, bias,
                                           attn_w, attn_b, proj_h, proj_p, out);
}